// Round 7
// baseline (2944548.828 us; speedup 1.0000x reference)
//
#include <hip/hip_runtime.h>
#include <stdint.h>

#define B_ 64
#define T_ 2048
#define F_ 128
#define H_ 256
#define TC_ 1022

typedef __bf16 bf16x8 __attribute__((ext_vector_type(8)));
typedef float f32x4 __attribute__((ext_vector_type(4)));
typedef unsigned long long u64;

__device__ __forceinline__ ushort f2bf(float f) {
    uint32_t u = __builtin_bit_cast(uint32_t, f);
    u += 0x7FFFu + ((u >> 16) & 1u);
    return (ushort)(u >> 16);
}
__device__ __forceinline__ float sigmoidf_(float x) { return 1.f / (1.f + __expf(-x)); }
__device__ __forceinline__ float tanhf_(float x) {
    x = fminf(15.f, fmaxf(-15.f, x));
    float e = __expf(2.f * x);
    return (e - 1.f) / (e + 1.f);
}

// ---- Kernel 1: sum of squares over T for F.normalize(dim=1) ----
__global__ __launch_bounds__(128) void k_sqsum(const float* __restrict__ in,
                                               float* __restrict__ sq) {
    int b = blockIdx.x >> 4, tq = blockIdx.x & 15, f = threadIdx.x;
    const float* p = in + ((size_t)b * T_ + (size_t)tq * 128) * F_ + f;
    float acc = 0.f;
#pragma unroll 8
    for (int t = 0; t < 128; ++t) { float v = p[(size_t)t * F_]; acc += v * v; }
    atomicAdd(&sq[b * F_ + f], acc);
}

// ---- Kernel 2: weight repack to bf16 block-row order; bias combine ----
// wbf[g2][m][k]: g2 = unit>>2 (0..63), m = uu*4+gate, k: [0,64)=w_ih, [64,320)=w_hh
__global__ __launch_bounds__(256) void k_prep(const float* __restrict__ wih, const float* __restrict__ whh,
                                              const float* __restrict__ bih, const float* __restrict__ bhh,
                                              ushort* __restrict__ wbf, float* __restrict__ bias) {
    int e = blockIdx.x * 256 + threadIdx.x;
    if (e < 64 * 16 * 320) {
        int g = e / 5120, m = (e / 320) & 15, k = e % 320;
        int j = (m & 3) * 256 + g * 4 + (m >> 2);  // gate*256 + unit
        float v = (k < 64) ? wih[j * 64 + k] : whh[j * 256 + (k - 64)];
        wbf[e] = f2bf(v);
    }
    if (e < 1024) bias[e] = bih[e] + bhh[e];
}

// ---- Kernel 3: fused normalize + conv1d(K=5,S=2) + bias + relu -> li bf16 [tc][b][72pad] ----
__global__ __launch_bounds__(256) void k_conv(const float* __restrict__ in, const float* __restrict__ cw,
                                              const float* __restrict__ cb, const float* __restrict__ sq,
                                              ushort* __restrict__ li) {
    __shared__ float rn[128];
    __shared__ __align__(16) float xs[67 * 129];
    __shared__ __align__(16) float wl[80 * 68];
    int b = blockIdx.x >> 5, tile = blockIdx.x & 31;
    int tc0 = tile * 32;
    int tid = threadIdx.x;
    if (tid < 128) { float ss = sq[b * 128 + tid]; rn[tid] = 1.f / fmaxf(sqrtf(ss), 1e-12f); }
    __syncthreads();
    const float* ip = in + ((size_t)b * T_ + (size_t)(2 * tc0)) * F_;
    for (int i = tid; i < 67 * 128; i += 256) {
        int r = i >> 7, f = i & 127;
        int t = 2 * tc0 + r;
        xs[r * 129 + f] = (t < T_) ? ip[(size_t)r * F_ + f] * rn[f] : 0.f;
    }
    int cg = tid & 15, tcg = tid >> 4;
    float a00 = 0, a01 = 0, a10 = 0, a11 = 0, a20 = 0, a21 = 0, a30 = 0, a31 = 0;
    for (int fc = 0; fc < 8; ++fc) {
        __syncthreads();
        for (int i = tid; i < 64 * 80; i += 256) {
            int c = i / 80, j = i - c * 80;
            wl[j * 68 + c] = cw[c * 640 + fc * 80 + j];
        }
        __syncthreads();
#pragma unroll
        for (int fi = 0; fi < 16; ++fi) {
#pragma unroll
            for (int k = 0; k < 5; ++k) {
                const float4 w4 = *(const float4*)&wl[(fi * 5 + k) * 68 + cg * 4];
                float x0 = xs[(4 * tcg + k) * 129 + fc * 16 + fi];
                float x1 = xs[(4 * tcg + 2 + k) * 129 + fc * 16 + fi];
                a00 += w4.x * x0; a01 += w4.x * x1;
                a10 += w4.y * x0; a11 += w4.y * x1;
                a20 += w4.z * x0; a21 += w4.z * x1;
                a30 += w4.w * x0; a31 += w4.w * x1;
            }
        }
    }
    float bc0 = cb[cg * 4 + 0], bc1 = cb[cg * 4 + 1], bc2 = cb[cg * 4 + 2], bc3 = cb[cg * 4 + 3];
#pragma unroll
    for (int tt = 0; tt < 2; ++tt) {
        int tc = tc0 + tcg * 2 + tt;
        if (tc < TC_) {
            float v0 = fmaxf((tt ? a01 : a00) + bc0, 0.f);
            float v1 = fmaxf((tt ? a11 : a10) + bc1, 0.f);
            float v2 = fmaxf((tt ? a21 : a20) + bc2, 0.f);
            float v3 = fmaxf((tt ? a31 : a30) + bc3, 0.f);
            uint2 pk;
            pk.x = (uint32_t)f2bf(v0) | ((uint32_t)f2bf(v1) << 16);
            pk.y = (uint32_t)f2bf(v2) | ((uint32_t)f2bf(v3) << 16);
            *reinterpret_cast<uint2*>(&li[((size_t)tc * 64 + b) * 72 + cg * 4]) = pk;
        }
    }
}

// ---- Kernel 4: LSTM scan with XCD-affinity election. 128 blocks launched; each block reads
// HW_REG_XCC_ID and claims a slot on its XCD; the 16th claimer CASes its XCD as winner. The
// 16 winning blocks (roles 0..15) run the scan; all others exit. All workers share ONE XCD's
// L2, so the h exchange uses plain stores (write-through to L2) + sc0 loads (L1 bypass) —
// no MALL round trips. Per step: producer stores h cells (coalesced, [ucell][b] layout) ->
// s_waitcnt vmcnt(0) (L2 ack) -> per-wave flag store. Consumer: poll 128 flags (sc0) ->
// single coalesced bulk sc0 read of 4096 u64 cells -> LDS stage -> ds_read_b128 fragments.
// WAR: parity double-buffer; flag>=t+1 proves that wave's step-t bulk reads completed (data
// dependence through MFMA -> h-store -> drain -> flag). Polls guard-bounded (fail, not hang).
__global__ __launch_bounds__(512) void k_scan(const ushort* __restrict__ li,
                                              const ushort* __restrict__ wbf,
                                              const float* __restrict__ bias,
                                              u64* __restrict__ hbuf,
                                              uint* __restrict__ flags,
                                              int* __restrict__ claim,
                                              int* __restrict__ winner,
                                              float* __restrict__ hfin) {
    __shared__ __align__(16) ushort Hs[64 * 264];  // h [b][256+8 pad] bf16, rows 528B
    __shared__ int s_role;
    int tid = threadIdx.x;
    // ---- Election (one scalar path per block) ----
    if (tid == 0) {
        uint xcc;
        asm volatile("s_getreg_b32 %0, hwreg(HW_REG_XCC_ID)" : "=s"(xcc));
        xcc &= 7u;
        int slot = atomicAdd(&claim[xcc], 1);
        if (slot == 15) atomicCAS(winner, -1, (int)xcc);
        int w = -1, guard = 0;
        do {
            w = __hip_atomic_load(winner, __ATOMIC_RELAXED, __HIP_MEMORY_SCOPE_AGENT);
        } while (w == -1 && ++guard < (1 << 19));
        s_role = ((int)xcc == w && slot < 16) ? slot : -1;
    }
    __syncthreads();
    int g = s_role;
    if (g < 0) return;

    int lane = tid & 63, wave = tid >> 6, l16 = lane & 15, quad = lane >> 4;
    int mi = wave & 3, a = wave >> 2;  // a in {0,1}
    int bb = a * 16 + l16;             // tile0 batch; tile1 batch = bb+32
    int u = g * 16 + mi * 4 + quad;
    // Stationary A-fragments: the wave's 16 gate-rows (g2 = 4g+mi), k-slice quad*8.
    bf16x8 af[10];
    const ushort* wp = wbf + ((size_t)((g * 4 + mi) * 16 + l16)) * 320 + quad * 8;
#pragma unroll
    for (int s = 0; s < 10; ++s) af[s] = *(const bf16x8*)(wp + s * 32);
    float bi = bias[u], bf2 = bias[256 + u], bg = bias[512 + u], bo = bias[768 + u];
    float cs0 = 0.f, cs1 = 0.f;
    uint* myflag = flags + g * 8 + wave;
#pragma unroll 1
    for (int t = 0; t < TC_; ++t) {
        // xt fragments for both tiles: plain cached loads, overlap the poll.
        const ushort* xp0 = li + ((size_t)t * 64 + bb) * 72 + quad * 8;
        const ushort* xp1 = xp0 + 32 * 72;
        bf16x8 x00 = *(const bf16x8*)xp0;
        bf16x8 x01 = *(const bf16x8*)(xp0 + 32);
        bf16x8 x10 = *(const bf16x8*)xp1;
        bf16x8 x11 = *(const bf16x8*)(xp1 + 32);
        f32x4 a00 = {0.f, 0.f, 0.f, 0.f}, a01 = {0.f, 0.f, 0.f, 0.f};
        f32x4 a10 = {0.f, 0.f, 0.f, 0.f}, a11 = {0.f, 0.f, 0.f, 0.f};
        a00 = __builtin_amdgcn_mfma_f32_16x16x32_bf16(af[0], x00, a00, 0, 0, 0);
        a10 = __builtin_amdgcn_mfma_f32_16x16x32_bf16(af[0], x10, a10, 0, 0, 0);
        a01 = __builtin_amdgcn_mfma_f32_16x16x32_bf16(af[1], x01, a01, 0, 0, 0);
        a11 = __builtin_amdgcn_mfma_f32_16x16x32_bf16(af[1], x11, a11, 0, 0, 0);
        if (t > 0) {
            // Phase 1: flag poll via sc0 loads (L1 bypass -> shared L2).
            int guard = 0;
            while (true) {
                uint f0, f1;
                asm volatile(
                    "global_load_dword %0, %2, off sc0\n\t"
                    "global_load_dword %1, %3, off sc0\n\t"
                    "s_waitcnt vmcnt(0)"
                    : "=v"(f0), "=v"(f1)
                    : "v"(flags + lane), "v"(flags + 64 + lane)
                    : "memory");
                bool ok = (f0 >= (uint)t) && (f1 >= (uint)t);
                if (__ballot(ok) == ~0ull || ++guard >= (1 << 15)) break;
            }
            // Phase 2: single coalesced bulk sc0 read of the whole h image (4096 cells).
            const u64* src = hbuf + ((size_t)((t - 1) & 1) << 12);
            u64 vv[8];
#pragma unroll
            for (int k = 0; k < 8; ++k) {
                int idx = (((k + g) & 7) << 9) + tid;  // block-staggered, lane-coalesced
                asm volatile("global_load_dwordx2 %0, %1, off sc0"
                             : "=v"(vv[k]) : "v"(src + idx));
            }
            asm volatile("s_waitcnt vmcnt(0)"
                         : "+v"(vv[0]), "+v"(vv[1]), "+v"(vv[2]), "+v"(vv[3]),
                           "+v"(vv[4]), "+v"(vv[5]), "+v"(vv[6]), "+v"(vv[7])
                         :: "memory");
            // Stage raw cells into LDS: cell idx -> ucell c = idx>>6, batch b = idx&63.
#pragma unroll
            for (int k = 0; k < 8; ++k) {
                int idx = (((k + g) & 7) << 9) + tid;
                int c = idx >> 6, b = idx & 63;
                *(uint2*)&Hs[b * 264 + c * 4] = __builtin_bit_cast(uint2, vv[k]);
            }
            __syncthreads();  // LDS h tile ready
            const ushort* h0 = &Hs[bb * 264 + quad * 8];
            const ushort* h1 = h0 + 32 * 264;
#pragma unroll
            for (int s = 0; s < 8; ++s) {
                bf16x8 bh0 = *(const bf16x8*)(h0 + s * 32);
                bf16x8 bh1 = *(const bf16x8*)(h1 + s * 32);
                if (s & 1) {
                    a01 = __builtin_amdgcn_mfma_f32_16x16x32_bf16(af[2 + s], bh0, a01, 0, 0, 0);
                    a11 = __builtin_amdgcn_mfma_f32_16x16x32_bf16(af[2 + s], bh1, a11, 0, 0, 0);
                } else {
                    a00 = __builtin_amdgcn_mfma_f32_16x16x32_bf16(af[2 + s], bh0, a00, 0, 0, 0);
                    a10 = __builtin_amdgcn_mfma_f32_16x16x32_bf16(af[2 + s], bh1, a10, 0, 0, 0);
                }
            }
        }
        float hv0 = 0.f, hv1 = 0.f;
#pragma unroll
        for (int j = 0; j < 2; ++j) {
            f32x4& p = j ? a10 : a00;
            f32x4& q = j ? a11 : a01;
            float& cs = j ? cs1 : cs0;
            float gi = p[0] + q[0] + bi, gf = p[1] + q[1] + bf2;
            float gg = p[2] + q[2] + bg, go = p[3] + q[3] + bo;
            float ii = sigmoidf_(gi), ff = sigmoidf_(gf), g2 = tanhf_(gg), oo = sigmoidf_(go);
            cs = ff * cs + ii * g2;
            float hv = oo * tanhf_(cs);
            if (j) hv1 = hv; else hv0 = hv;
        }
        if (t == TC_ - 1) {
            hfin[u * 64 + bb] = hv0;
            hfin[u * 64 + bb + 32] = hv1;
        } else {
            u64* dstbase = hbuf + ((size_t)(t & 1) << 12);
#pragma unroll
            for (int j = 0; j < 2; ++j) {
                ushort hb = f2bf(j ? hv1 : hv0);
                uint v1 = (uint)__shfl((int)hb, lane + 16);   // quad q gets q+1's value
                uint pk = ((uint)hb & 0xFFFFu) | (v1 << 16);  // valid on quads 0,2
                uint v2 = (uint)__shfl((int)pk, lane + 32);   // quad 0 gets quad 2's pair
                if (quad == 0) {
                    u64 w = (u64)pk | ((u64)v2 << 32);        // units 4*ucell..+3 packed
                    int bbj = bb + 32 * j;
                    u64* dst = dstbase + (size_t)(g * 4 + mi) * 64 + bbj;  // [ucell][b]: coalesced
                    asm volatile("global_store_dwordx2 %0, %1, off"
                                 :: "v"(dst), "v"(w) : "memory");
                }
            }
            asm volatile("s_waitcnt vmcnt(0)" ::: "memory");  // h stores acked at shared L2
            if (lane == 0) {
                uint fv = (uint)(t + 1);
                asm volatile("global_store_dword %0, %1, off"
                             :: "v"(myflag), "v"(fv) : "memory");
            }
        }
    }
}

// ---- Kernel 5: out[b][o] = h_final[:,b] . lin_w[o,:] + lin_b[o] ----
__global__ __launch_bounds__(64) void k_fin(const float* __restrict__ hfin, const float* __restrict__ lw,
                                            const float* __restrict__ lb, float* __restrict__ out) {
    int o = blockIdx.x, b = threadIdx.x;
    float acc = lb[o];
    const float* wp = lw + o * 256;
#pragma unroll 4
    for (int u2 = 0; u2 < 256; ++u2) acc += hfin[u2 * 64 + b] * wp[u2];
    out[b * 10 + o] = acc;
}

extern "C" void kernel_launch(void* const* d_in, const int* in_sizes, int n_in,
                              void* d_out, int out_size, void* d_ws, size_t ws_size,
                              hipStream_t stream) {
    const float* in  = (const float*)d_in[0];
    // d_in[1] ("r") unused
    const float* cw  = (const float*)d_in[2];
    const float* cb  = (const float*)d_in[3];
    const float* wih = (const float*)d_in[4];
    const float* whh = (const float*)d_in[5];
    const float* bih = (const float*)d_in[6];
    const float* bhh = (const float*)d_in[7];
    const float* lw  = (const float*)d_in[8];
    const float* lb  = (const float*)d_in[9];
    float* out = (float*)d_out;

    char* ws = (char*)d_ws;
    float*  sq     = (float*)(ws + 0);         // 32768 B
    u64*    hbuf   = (u64*)(ws + 32768);       // 65536 B: 2 parity x 4096 cells x 8B
    uint*   flags  = (uint*)(ws + 98304);      // 512 B: 128 per-wave flags
    int*    claim  = (int*)(ws + 98816);       // 32 B: per-XCD claim counters
    int*    winner = (int*)(ws + 98848);       // 4 B
    float*  bias   = (float*)(ws + 102400);    // 4096 B
    float*  hfin   = (float*)(ws + 106496);    // 65536 B  [u][b] fp32
    ushort* wbf    = (ushort*)(ws + 172032);   // 655360 B [g2][16][320] bf16
    ushort* li     = (ushort*)(ws + 827392);   // 9418752 B [tc][b][72] bf16

    hipMemsetAsync(sq, 0, 32768, stream);
    hipMemsetAsync(flags, 0, 512 + 32, stream);   // flags + claim counters
    hipMemsetAsync(winner, 0xFF, 4, stream);      // winner = -1

    k_sqsum<<<1024, 128, 0, stream>>>(in, sq);
    k_prep<<<1280, 256, 0, stream>>>(wih, whh, bih, bhh, wbf, bias);
    k_conv<<<2048, 256, 0, stream>>>(in, cw, cb, sq, li);
    k_scan<<<128, 512, 0, stream>>>(li, wbf, bias, hbuf, flags, claim, winner, hfin);
    k_fin<<<10, 64, 0, stream>>>(hfin, lw, lb, out);
}

// Round 8
// 21256.619 us; speedup vs baseline: 138.5239x; 138.5239x over previous
//
#include <hip/hip_runtime.h>
#include <stdint.h>

#define B_ 64
#define T_ 2048
#define F_ 128
#define H_ 256
#define TC_ 1022

typedef __bf16 bf16x8 __attribute__((ext_vector_type(8)));
typedef float f32x4 __attribute__((ext_vector_type(4)));
typedef unsigned long long u64;

__device__ __forceinline__ ushort f2bf(float f) {
    uint32_t u = __builtin_bit_cast(uint32_t, f);
    u += 0x7FFFu + ((u >> 16) & 1u);
    return (ushort)(u >> 16);
}
__device__ __forceinline__ float sigmoidf_(float x) { return 1.f / (1.f + __expf(-x)); }
__device__ __forceinline__ float tanhf_(float x) {
    x = fminf(15.f, fmaxf(-15.f, x));
    float e = __expf(2.f * x);
    return (e - 1.f) / (e + 1.f);
}

// ---- Kernel 1: sum of squares over T for F.normalize(dim=1) ----
__global__ __launch_bounds__(128) void k_sqsum(const float* __restrict__ in,
                                               float* __restrict__ sq) {
    int b = blockIdx.x >> 4, tq = blockIdx.x & 15, f = threadIdx.x;
    const float* p = in + ((size_t)b * T_ + (size_t)tq * 128) * F_ + f;
    float acc = 0.f;
#pragma unroll 8
    for (int t = 0; t < 128; ++t) { float v = p[(size_t)t * F_]; acc += v * v; }
    atomicAdd(&sq[b * F_ + f], acc);
}

// ---- Kernel 2: weight repack to bf16 block-row order; bias combine ----
__global__ __launch_bounds__(256) void k_prep(const float* __restrict__ wih, const float* __restrict__ whh,
                                              const float* __restrict__ bih, const float* __restrict__ bhh,
                                              ushort* __restrict__ wbf, float* __restrict__ bias) {
    int e = blockIdx.x * 256 + threadIdx.x;
    if (e < 64 * 16 * 320) {
        int g = e / 5120, m = (e / 320) & 15, k = e % 320;
        int j = (m & 3) * 256 + g * 4 + (m >> 2);  // gate*256 + unit
        float v = (k < 64) ? wih[j * 64 + k] : whh[j * 256 + (k - 64)];
        wbf[e] = f2bf(v);
    }
    if (e < 1024) bias[e] = bih[e] + bhh[e];
}

// ---- Kernel 3: fused normalize + conv1d(K=5,S=2) + bias + relu -> li bf16 [tc][b][72pad] ----
__global__ __launch_bounds__(256) void k_conv(const float* __restrict__ in, const float* __restrict__ cw,
                                              const float* __restrict__ cb, const float* __restrict__ sq,
                                              ushort* __restrict__ li) {
    __shared__ float rn[128];
    __shared__ __align__(16) float xs[67 * 129];
    __shared__ __align__(16) float wl[80 * 68];
    int b = blockIdx.x >> 5, tile = blockIdx.x & 31;
    int tc0 = tile * 32;
    int tid = threadIdx.x;
    if (tid < 128) { float ss = sq[b * 128 + tid]; rn[tid] = 1.f / fmaxf(sqrtf(ss), 1e-12f); }
    __syncthreads();
    const float* ip = in + ((size_t)b * T_ + (size_t)(2 * tc0)) * F_;
    for (int i = tid; i < 67 * 128; i += 256) {
        int r = i >> 7, f = i & 127;
        int t = 2 * tc0 + r;
        xs[r * 129 + f] = (t < T_) ? ip[(size_t)r * F_ + f] * rn[f] : 0.f;
    }
    int cg = tid & 15, tcg = tid >> 4;
    float a00 = 0, a01 = 0, a10 = 0, a11 = 0, a20 = 0, a21 = 0, a30 = 0, a31 = 0;
    for (int fc = 0; fc < 8; ++fc) {
        __syncthreads();
        for (int i = tid; i < 64 * 80; i += 256) {
            int c = i / 80, j = i - c * 80;
            wl[j * 68 + c] = cw[c * 640 + fc * 80 + j];
        }
        __syncthreads();
#pragma unroll
        for (int fi = 0; fi < 16; ++fi) {
#pragma unroll
            for (int k = 0; k < 5; ++k) {
                const float4 w4 = *(const float4*)&wl[(fi * 5 + k) * 68 + cg * 4];
                float x0 = xs[(4 * tcg + k) * 129 + fc * 16 + fi];
                float x1 = xs[(4 * tcg + 2 + k) * 129 + fc * 16 + fi];
                a00 += w4.x * x0; a01 += w4.x * x1;
                a10 += w4.y * x0; a11 += w4.y * x1;
                a20 += w4.z * x0; a21 += w4.z * x1;
                a30 += w4.w * x0; a31 += w4.w * x1;
            }
        }
    }
    float bc0 = cb[cg * 4 + 0], bc1 = cb[cg * 4 + 1], bc2 = cb[cg * 4 + 2], bc3 = cb[cg * 4 + 3];
#pragma unroll
    for (int tt = 0; tt < 2; ++tt) {
        int tc = tc0 + tcg * 2 + tt;
        if (tc < TC_) {
            float v0 = fmaxf((tt ? a01 : a00) + bc0, 0.f);
            float v1 = fmaxf((tt ? a11 : a10) + bc1, 0.f);
            float v2 = fmaxf((tt ? a21 : a20) + bc2, 0.f);
            float v3 = fmaxf((tt ? a31 : a30) + bc3, 0.f);
            uint2 pk;
            pk.x = (uint32_t)f2bf(v0) | ((uint32_t)f2bf(v1) << 16);
            pk.y = (uint32_t)f2bf(v2) | ((uint32_t)f2bf(v3) << 16);
            *reinterpret_cast<uint2*>(&li[((size_t)tc * 64 + b) * 72 + cg * 4]) = pk;
        }
    }
}

// ---- Kernel 4: LSTM scan, XCD-elected 16 blocks x 512 threads on ONE XCD.
// Data cells: u64 = (h[2uc]|t<<16) | ((h[2uc+1]|t<<16)<<32), layout [uc:128][b:64] per parity.
// Stores: __hip_atomic AGENT (R6-proven write-through) + vmcnt drain + per-wave flag.
// Loads: sc0 fast path (shared local L2) with STICKY ESCALATION to agent loads —
// flag poll escalates (pmode) after 192 dry polls at t>4; tagged bulk escalates (bmode)
// after 24 post-flag-pass tag failures (flags passed => data at coherence point =>
// persistent mismatch = stale local L2 line). Worst case ~= R6 semantics.
// LDS: conflict-free layout [slot=s*4+quad][b][16B]; frag reads are lane-linear.
// xt double-buffered in regs: next step's loads issue after the flag store.
__global__ __launch_bounds__(512) void k_scan(const ushort* __restrict__ li,
                                              const ushort* __restrict__ wbf,
                                              const float* __restrict__ bias,
                                              u64* __restrict__ hbuf,
                                              uint* __restrict__ flags,
                                              int* __restrict__ claim,
                                              int* __restrict__ winner,
                                              float* __restrict__ hfin) {
    __shared__ __align__(16) ushort Hs[32 * 64 * 8];  // 32 slots x 64 batches x 16B = 32KB
    __shared__ int s_role;
    int tid = threadIdx.x;
    if (tid == 0) {
        uint xcc;
        asm volatile("s_getreg_b32 %0, hwreg(HW_REG_XCC_ID)" : "=s"(xcc));
        xcc &= 7u;
        int slot = atomicAdd(&claim[xcc], 1);
        if (slot == 15) atomicCAS(winner, -1, (int)xcc);
        int w = -1, guard = 0;
        do {
            w = __hip_atomic_load(winner, __ATOMIC_RELAXED, __HIP_MEMORY_SCOPE_AGENT);
        } while (w == -1 && ++guard < (1 << 19));
        s_role = ((int)xcc == w && slot < 16) ? slot : -1;
    }
    __syncthreads();
    int g = s_role;
    if (g < 0) return;

    int lane = tid & 63, wave = tid >> 6, l16 = lane & 15, quad = lane >> 4;
    int mi = wave & 3, a = wave >> 2;  // a in {0,1}
    int bb = a * 16 + l16;             // tile0 batch; tile1 = bb+32
    int u = g * 16 + mi * 4 + quad;
    bf16x8 af[10];
    const ushort* wp = wbf + ((size_t)((g * 4 + mi) * 16 + l16)) * 320 + quad * 8;
#pragma unroll
    for (int s = 0; s < 10; ++s) af[s] = *(const bf16x8*)(wp + s * 32);
    float bi = bias[u], bf2 = bias[256 + u], bg = bias[512 + u], bo = bias[768 + u];
    float cs0 = 0.f, cs1 = 0.f;
    uint* myflag = flags + g * 8 + wave;
    char* HsB = (char*)Hs;
    int pmode = 0, bmode = 0;
    // preload xt for t=0
    const ushort* xpp = li + ((size_t)0 * 64 + bb) * 72 + quad * 8;
    bf16x8 x00 = *(const bf16x8*)xpp;
    bf16x8 x01 = *(const bf16x8*)(xpp + 32);
    bf16x8 x10 = *(const bf16x8*)(xpp + 32 * 72);
    bf16x8 x11 = *(const bf16x8*)(xpp + 32 * 72 + 32);
#pragma unroll 1
    for (int t = 0; t < TC_; ++t) {
        f32x4 a00 = {0.f, 0.f, 0.f, 0.f}, a01 = {0.f, 0.f, 0.f, 0.f};
        f32x4 a10 = {0.f, 0.f, 0.f, 0.f}, a11 = {0.f, 0.f, 0.f, 0.f};
        if (t > 0) {
            uint tg = (uint)(t - 1);
            // Phase 1: flag poll (fast: sc0 L2; escalated: agent).
            int polls = 0;
            while (true) {
                uint f0, f1;
                if (pmode == 0) {
                    asm volatile(
                        "global_load_dword %0, %2, off sc0\n\t"
                        "global_load_dword %1, %3, off sc0\n\t"
                        "s_waitcnt vmcnt(0)"
                        : "=v"(f0), "=v"(f1)
                        : "v"(flags + lane), "v"(flags + 64 + lane)
                        : "memory");
                } else {
                    f0 = __hip_atomic_load(flags + lane, __ATOMIC_RELAXED, __HIP_MEMORY_SCOPE_AGENT);
                    f1 = __hip_atomic_load(flags + 64 + lane, __ATOMIC_RELAXED, __HIP_MEMORY_SCOPE_AGENT);
                }
                bool ok = (f0 >= (uint)t) && (f1 >= (uint)t);
                if (__ballot(ok) == ~0ull) break;
                ++polls;
                if (polls == 192 && t > 4) pmode = 1;
                if (polls >= (1 << 15)) break;
            }
            // Phase 2: tagged bulk read (fast: sc0; escalated: agent). Retry on tag fail.
            const u64* src = hbuf + ((size_t)(tg & 1) << 13);
            u64 vv[16];
            int rt = 0;
            while (true) {
                if (bmode == 0) {
#pragma unroll
                    for (int k = 0; k < 16; ++k) {
                        int idx = (((k + g) & 15) << 9) + tid;
                        asm volatile("global_load_dwordx2 %0, %1, off sc0"
                                     : "=v"(vv[k]) : "v"(src + idx));
                    }
                    asm volatile("s_waitcnt vmcnt(0)"
                                 : "+v"(vv[0]), "+v"(vv[1]), "+v"(vv[2]), "+v"(vv[3]),
                                   "+v"(vv[4]), "+v"(vv[5]), "+v"(vv[6]), "+v"(vv[7]),
                                   "+v"(vv[8]), "+v"(vv[9]), "+v"(vv[10]), "+v"(vv[11]),
                                   "+v"(vv[12]), "+v"(vv[13]), "+v"(vv[14]), "+v"(vv[15])
                                 :: "memory");
                } else {
#pragma unroll
                    for (int k = 0; k < 16; ++k) {
                        int idx = (((k + g) & 15) << 9) + tid;
                        vv[k] = __hip_atomic_load(src + idx, __ATOMIC_RELAXED, __HIP_MEMORY_SCOPE_AGENT);
                    }
                }
                uint m = 0;
#pragma unroll
                for (int k = 0; k < 16; ++k)
                    m |= (((uint)(vv[k] >> 16) & 0xFFFFu) ^ tg) | (((uint)(vv[k] >> 48)) ^ tg);
                if (__all(m == 0)) break;
                if (++rt == 24) bmode = 1;
                if (rt >= 4096) break;
            }
            // Stage into conflict-free LDS layout.
#pragma unroll
            for (int k = 0; k < 16; ++k) {
                int idx = (((k + g) & 15) << 9) + tid;
                int uc = idx >> 6, b = idx & 63;
                uint pk = ((uint)vv[k] & 0xFFFFu) | (((uint)(vv[k] >> 32) & 0xFFFFu) << 16);
                int slot = ((uc >> 4) << 2) | ((uc >> 2) & 3);
                *(uint*)&HsB[(slot * 64 + b) * 16 + ((uc & 3) << 2)] = pk;
            }
            __syncthreads();
        }
        // x-part MFMAs (xt in regs since last iteration's prefetch).
        a00 = __builtin_amdgcn_mfma_f32_16x16x32_bf16(af[0], x00, a00, 0, 0, 0);
        a10 = __builtin_amdgcn_mfma_f32_16x16x32_bf16(af[0], x10, a10, 0, 0, 0);
        a01 = __builtin_amdgcn_mfma_f32_16x16x32_bf16(af[1], x01, a01, 0, 0, 0);
        a11 = __builtin_amdgcn_mfma_f32_16x16x32_bf16(af[1], x11, a11, 0, 0, 0);
        if (t > 0) {
#pragma unroll
            for (int s = 0; s < 8; ++s) {
                const char* base = HsB + ((s * 4 + quad) * 64) * 16;
                bf16x8 bh0 = *(const bf16x8*)(base + bb * 16);
                bf16x8 bh1 = *(const bf16x8*)(base + (bb + 32) * 16);
                if (s & 1) {
                    a01 = __builtin_amdgcn_mfma_f32_16x16x32_bf16(af[2 + s], bh0, a01, 0, 0, 0);
                    a11 = __builtin_amdgcn_mfma_f32_16x16x32_bf16(af[2 + s], bh1, a11, 0, 0, 0);
                } else {
                    a00 = __builtin_amdgcn_mfma_f32_16x16x32_bf16(af[2 + s], bh0, a00, 0, 0, 0);
                    a10 = __builtin_amdgcn_mfma_f32_16x16x32_bf16(af[2 + s], bh1, a10, 0, 0, 0);
                }
            }
        }
        float hv0 = 0.f, hv1 = 0.f;
#pragma unroll
        for (int j = 0; j < 2; ++j) {
            f32x4& p = j ? a10 : a00;
            f32x4& q = j ? a11 : a01;
            float& cs = j ? cs1 : cs0;
            float gi = p[0] + q[0] + bi, gf = p[1] + q[1] + bf2;
            float gg = p[2] + q[2] + bg, go = p[3] + q[3] + bo;
            float ii = sigmoidf_(gi), ff = sigmoidf_(gf), g2 = tanhf_(gg), oo = sigmoidf_(go);
            cs = ff * cs + ii * g2;
            float hv = oo * tanhf_(cs);
            if (j) hv1 = hv; else hv0 = hv;
        }
        if (t == TC_ - 1) {
            hfin[u * 64 + bb] = hv0;
            hfin[u * 64 + bb + 32] = hv1;
        } else {
            u64* dstbase = hbuf + ((size_t)(t & 1) << 13);
            uint tg2 = ((uint)t) << 16;
#pragma unroll
            for (int j = 0; j < 2; ++j) {
                ushort hb = f2bf(j ? hv1 : hv0);
                uint v1 = (uint)__shfl((int)hb, (lane + 16) & 63);  // quad q gets q+1's h
                if ((quad & 1) == 0) {
                    u64 w = (u64)(((uint)hb & 0xFFFFu) | tg2) |
                            ((u64)((v1 & 0xFFFFu) | tg2) << 32);
                    int uc = g * 8 + mi * 2 + (quad >> 1);
                    __hip_atomic_store(dstbase + (size_t)uc * 64 + bb + 32 * j, w,
                                       __ATOMIC_RELAXED, __HIP_MEMORY_SCOPE_AGENT);
                }
            }
            asm volatile("s_waitcnt vmcnt(0)" ::: "memory");  // data acked at coherence point
            if (lane == 0)
                __hip_atomic_store(myflag, (uint)(t + 1), __ATOMIC_RELAXED, __HIP_MEMORY_SCOPE_AGENT);
        }
        // Prefetch next xt AFTER the drain+flag (doesn't delay publish; lands during next poll).
        int tn = (t + 1 < TC_) ? t + 1 : t;
        const ushort* xpn = li + ((size_t)tn * 64 + bb) * 72 + quad * 8;
        x00 = *(const bf16x8*)xpn;
        x01 = *(const bf16x8*)(xpn + 32);
        x10 = *(const bf16x8*)(xpn + 32 * 72);
        x11 = *(const bf16x8*)(xpn + 32 * 72 + 32);
    }
}

// ---- Kernel 5: out[b][o] = h_final[:,b] . lin_w[o,:] + lin_b[o] ----
__global__ __launch_bounds__(64) void k_fin(const float* __restrict__ hfin, const float* __restrict__ lw,
                                            const float* __restrict__ lb, float* __restrict__ out) {
    int o = blockIdx.x, b = threadIdx.x;
    float acc = lb[o];
    const float* wp = lw + o * 256;
#pragma unroll 4
    for (int u2 = 0; u2 < 256; ++u2) acc += hfin[u2 * 64 + b] * wp[u2];
    out[b * 10 + o] = acc;
}

extern "C" void kernel_launch(void* const* d_in, const int* in_sizes, int n_in,
                              void* d_out, int out_size, void* d_ws, size_t ws_size,
                              hipStream_t stream) {
    const float* in  = (const float*)d_in[0];
    // d_in[1] ("r") unused
    const float* cw  = (const float*)d_in[2];
    const float* cb  = (const float*)d_in[3];
    const float* wih = (const float*)d_in[4];
    const float* whh = (const float*)d_in[5];
    const float* bih = (const float*)d_in[6];
    const float* bhh = (const float*)d_in[7];
    const float* lw  = (const float*)d_in[8];
    const float* lb  = (const float*)d_in[9];
    float* out = (float*)d_out;

    char* ws = (char*)d_ws;
    float*  sq     = (float*)(ws + 0);         // 32768 B
    u64*    hbuf   = (u64*)(ws + 32768);       // 131072 B: 2 parity x 8192 cells x 8B
    uint*   flags  = (uint*)(ws + 163840);     // 512 B: 128 per-wave flags
    int*    claim  = (int*)(ws + 164352);      // 32 B
    int*    winner = (int*)(ws + 164384);      // 4 B
    float*  bias   = (float*)(ws + 165888);    // 4096 B
    float*  hfin   = (float*)(ws + 169984);    // 65536 B  [u][b] fp32
    ushort* wbf    = (ushort*)(ws + 235520);   // 655360 B
    ushort* li     = (ushort*)(ws + 890880);   // 9418752 B [tc][b][72] bf16

    hipMemsetAsync(sq, 0, 32768, stream);
    hipMemsetAsync(hbuf, 0xFF, 131072, stream);   // tags invalid
    hipMemsetAsync(flags, 0, 512 + 32, stream);   // flags + claim
    hipMemsetAsync(winner, 0xFF, 4, stream);      // winner = -1

    k_sqsum<<<1024, 128, 0, stream>>>(in, sq);
    k_prep<<<1280, 256, 0, stream>>>(wih, whh, bih, bhh, wbf, bias);
    k_conv<<<2048, 256, 0, stream>>>(in, cw, cb, sq, li);
    k_scan<<<128, 512, 0, stream>>>(li, wbf, bias, hbuf, flags, claim, winner, hfin);
    k_fin<<<10, 64, 0, stream>>>(hfin, lw, lb, out);
}

// Round 9
// 2889.822 us; speedup vs baseline: 1018.9376x; 7.3557x over previous
//
#include <hip/hip_runtime.h>
#include <stdint.h>

#define B_ 64
#define T_ 2048
#define F_ 128
#define H_ 256
#define TC_ 1022

typedef __bf16 bf16x8 __attribute__((ext_vector_type(8)));
typedef float f32x4 __attribute__((ext_vector_type(4)));
typedef unsigned long long u64;

__device__ __forceinline__ ushort f2bf(float f) {
    uint32_t u = __builtin_bit_cast(uint32_t, f);
    u += 0x7FFFu + ((u >> 16) & 1u);
    return (ushort)(u >> 16);
}
__device__ __forceinline__ float sigmoidf_(float x) { return 1.f / (1.f + __expf(-x)); }
__device__ __forceinline__ float tanhf_(float x) {
    x = fminf(15.f, fmaxf(-15.f, x));
    float e = __expf(2.f * x);
    return (e - 1.f) / (e + 1.f);
}

// ---- Kernel 1: sum of squares over T for F.normalize(dim=1) ----
__global__ __launch_bounds__(128) void k_sqsum(const float* __restrict__ in,
                                               float* __restrict__ sq) {
    int b = blockIdx.x >> 4, tq = blockIdx.x & 15, f = threadIdx.x;
    const float* p = in + ((size_t)b * T_ + (size_t)tq * 128) * F_ + f;
    float acc = 0.f;
#pragma unroll 8
    for (int t = 0; t < 128; ++t) { float v = p[(size_t)t * F_]; acc += v * v; }
    atomicAdd(&sq[b * F_ + f], acc);
}

// ---- Kernel 2: weight repack to bf16 block-row order; bias combine ----
// wbf[g2][m][k]: g2 = unit>>2 (0..63), m = uu*4+gate, k: [0,64)=w_ih, [64,320)=w_hh
__global__ __launch_bounds__(256) void k_prep(const float* __restrict__ wih, const float* __restrict__ whh,
                                              const float* __restrict__ bih, const float* __restrict__ bhh,
                                              ushort* __restrict__ wbf, float* __restrict__ bias) {
    int e = blockIdx.x * 256 + threadIdx.x;
    if (e < 64 * 16 * 320) {
        int g = e / 5120, m = (e / 320) & 15, k = e % 320;
        int j = (m & 3) * 256 + g * 4 + (m >> 2);  // gate*256 + unit
        float v = (k < 64) ? wih[j * 64 + k] : whh[j * 256 + (k - 64)];
        wbf[e] = f2bf(v);
    }
    if (e < 1024) bias[e] = bih[e] + bhh[e];
}

// ---- Kernel 3: fused normalize + conv1d(K=5,S=2) + bias + relu -> li bf16 [tc][b][72pad] ----
__global__ __launch_bounds__(256) void k_conv(const float* __restrict__ in, const float* __restrict__ cw,
                                              const float* __restrict__ cb, const float* __restrict__ sq,
                                              ushort* __restrict__ li) {
    __shared__ float rn[128];
    __shared__ __align__(16) float xs[67 * 129];
    __shared__ __align__(16) float wl[80 * 68];
    int b = blockIdx.x >> 5, tile = blockIdx.x & 31;
    int tc0 = tile * 32;
    int tid = threadIdx.x;
    if (tid < 128) { float ss = sq[b * 128 + tid]; rn[tid] = 1.f / fmaxf(sqrtf(ss), 1e-12f); }
    __syncthreads();
    const float* ip = in + ((size_t)b * T_ + (size_t)(2 * tc0)) * F_;
    for (int i = tid; i < 67 * 128; i += 256) {
        int r = i >> 7, f = i & 127;
        int t = 2 * tc0 + r;
        xs[r * 129 + f] = (t < T_) ? ip[(size_t)r * F_ + f] * rn[f] : 0.f;
    }
    int cg = tid & 15, tcg = tid >> 4;
    float a00 = 0, a01 = 0, a10 = 0, a11 = 0, a20 = 0, a21 = 0, a30 = 0, a31 = 0;
    for (int fc = 0; fc < 8; ++fc) {
        __syncthreads();
        for (int i = tid; i < 64 * 80; i += 256) {
            int c = i / 80, j = i - c * 80;
            wl[j * 68 + c] = cw[c * 640 + fc * 80 + j];
        }
        __syncthreads();
#pragma unroll
        for (int fi = 0; fi < 16; ++fi) {
#pragma unroll
            for (int k = 0; k < 5; ++k) {
                const float4 w4 = *(const float4*)&wl[(fi * 5 + k) * 68 + cg * 4];
                float x0 = xs[(4 * tcg + k) * 129 + fc * 16 + fi];
                float x1 = xs[(4 * tcg + 2 + k) * 129 + fc * 16 + fi];
                a00 += w4.x * x0; a01 += w4.x * x1;
                a10 += w4.y * x0; a11 += w4.y * x1;
                a20 += w4.z * x0; a21 += w4.z * x1;
                a30 += w4.w * x0; a31 += w4.w * x1;
            }
        }
    }
    float bc0 = cb[cg * 4 + 0], bc1 = cb[cg * 4 + 1], bc2 = cb[cg * 4 + 2], bc3 = cb[cg * 4 + 3];
#pragma unroll
    for (int tt = 0; tt < 2; ++tt) {
        int tc = tc0 + tcg * 2 + tt;
        if (tc < TC_) {
            float v0 = fmaxf((tt ? a01 : a00) + bc0, 0.f);
            float v1 = fmaxf((tt ? a11 : a10) + bc1, 0.f);
            float v2 = fmaxf((tt ? a21 : a20) + bc2, 0.f);
            float v3 = fmaxf((tt ? a31 : a30) + bc3, 0.f);
            uint2 pk;
            pk.x = (uint32_t)f2bf(v0) | ((uint32_t)f2bf(v1) << 16);
            pk.y = (uint32_t)f2bf(v2) | ((uint32_t)f2bf(v3) << 16);
            *reinterpret_cast<uint2*>(&li[((size_t)tc * 64 + b) * 72 + cg * 4]) = pk;
        }
    }
}

// ---- Kernel 4: pod-structured LSTM scan. 16 blocks x 512 thr = 4 independent PODS of 4
// blocks. Pod p owns batches [16p,16p+16) (batch rows of the recurrence are independent!);
// within a pod, block q owns units [64q,64q+64). Wave w computes TWO M-tiles (32 gate rows,
// units 64q+8w..+8) for the pod's 16 batches; af (weights) stationary in regs (80 VGPR).
// Exchange (within pod only, agent scope / MALL — the R6-proven primitive):
//   producer: fire-and-forget tagged stores. Cell u64 = (h[2c]|t<<16) | ((h[2c+1]|t<<16)<<32),
//             layout [parity][pod][b:16][c:128]. No drain, no flag.
//   consumer: fused tagged poll+read of the pod image (4 cells/thread, coalesced, 16KB),
//             retry until all tags==t-1 (guard-bounded), stage to LDS, ds_read_b128 frags.
// WAR: parity double-buffer + chain argument (block at t+2 implies all pod siblings consumed
// t, since reaching t+1 required reading every sibling's t tags). Max intra-pod skew = 1.
__global__ __launch_bounds__(512) void k_scan(const ushort* __restrict__ li,
                                              const ushort* __restrict__ wbf,
                                              const float* __restrict__ bias,
                                              u64* __restrict__ hbuf,
                                              float* __restrict__ hfin) {
    __shared__ __align__(16) ushort Hs[16 * 264];  // h [b:16][256+8 pad] bf16, rows 528B
    int p = blockIdx.x >> 2, q = blockIdx.x & 3;
    int tid = threadIdx.x;
    int lane = tid & 63, wave = tid >> 6, l16 = lane & 15, quad = lane >> 4;
    int bb = p * 16 + l16;                    // global batch
    int g2a = q * 16 + 2 * wave, g2b = g2a + 1;
    int u0 = g2a * 4 + quad, u1 = g2b * 4 + quad;
    // Stationary A-fragments: two 16-row tiles (rows = l16 within each tile).
    bf16x8 af0[10], af1[10];
    const ushort* wp0 = wbf + ((size_t)(g2a * 16 + l16)) * 320 + quad * 8;
    const ushort* wp1 = wbf + ((size_t)(g2b * 16 + l16)) * 320 + quad * 8;
#pragma unroll
    for (int s = 0; s < 10; ++s) { af0[s] = *(const bf16x8*)(wp0 + s * 32);
                                   af1[s] = *(const bf16x8*)(wp1 + s * 32); }
    float bi0 = bias[u0], bf0 = bias[256 + u0], bg0 = bias[512 + u0], bo0 = bias[768 + u0];
    float bi1 = bias[u1], bf1 = bias[256 + u1], bg1 = bias[512 + u1], bo1 = bias[768 + u1];
    float cs0 = 0.f, cs1 = 0.f;
    // xt preload for t=0 (B-frags shared by both M-tiles)
    const ushort* xpp = li + ((size_t)0 * 64 + bb) * 72 + quad * 8;
    bf16x8 x0 = *(const bf16x8*)xpp;
    bf16x8 x1 = *(const bf16x8*)(xpp + 32);
#pragma unroll 1
    for (int t = 0; t < TC_; ++t) {
        f32x4 A0 = {0.f, 0.f, 0.f, 0.f}, A1 = {0.f, 0.f, 0.f, 0.f};
        // x-part MFMAs first (xt already in regs from prefetch).
        A0 = __builtin_amdgcn_mfma_f32_16x16x32_bf16(af0[0], x0, A0, 0, 0, 0);
        A1 = __builtin_amdgcn_mfma_f32_16x16x32_bf16(af1[0], x0, A1, 0, 0, 0);
        A0 = __builtin_amdgcn_mfma_f32_16x16x32_bf16(af0[1], x1, A0, 0, 0, 0);
        A1 = __builtin_amdgcn_mfma_f32_16x16x32_bf16(af1[1], x1, A1, 0, 0, 0);
        if (t > 0) {
            uint tg = (uint)(t - 1);
            // Fused tagged poll+read: this thread's 4 cells of the pod image.
            const u64* src = hbuf + ((size_t)((t - 1) & 1) << 13) + p * 2048 + tid * 4;
            u64 vv[4];
            bool ok;
            int guard = 0;
            do {
#pragma unroll
                for (int k = 0; k < 4; ++k)
                    vv[k] = __hip_atomic_load(src + k, __ATOMIC_RELAXED, __HIP_MEMORY_SCOPE_AGENT);
                uint m = 0;
#pragma unroll
                for (int k = 0; k < 4; ++k)
                    m |= (((uint)(vv[k] >> 16) & 0xFFFFu) ^ tg) | (((uint)(vv[k] >> 48)) ^ tg);
                ok = (m == 0);
            } while (!__all(ok) && ++guard < (1 << 14));
            // Stage to LDS: idx=4*tid -> b=idx>>7, c=idx&127; cell c = units {2c,2c+1}.
            {
                int b = tid >> 5, c0 = (tid * 4) & 127;
                uint4 w;
                w.x = ((uint)vv[0] & 0xFFFFu) | (((uint)(vv[0] >> 32) & 0xFFFFu) << 16);
                w.y = ((uint)vv[1] & 0xFFFFu) | (((uint)(vv[1] >> 32) & 0xFFFFu) << 16);
                w.z = ((uint)vv[2] & 0xFFFFu) | (((uint)(vv[2] >> 32) & 0xFFFFu) << 16);
                w.w = ((uint)vv[3] & 0xFFFFu) | (((uint)(vv[3] >> 32) & 0xFFFFu) << 16);
                *(uint4*)((char*)Hs + b * 528 + c0 * 4) = w;
            }
            __syncthreads();
            // h-part MFMAs: frag = Hs[row=l16][units s*32+quad*8 ..+8], shared by both tiles.
#pragma unroll
            for (int s = 0; s < 8; ++s) {
                bf16x8 bh = *(const bf16x8*)((const char*)Hs + l16 * 528 + s * 64 + quad * 16);
                A0 = __builtin_amdgcn_mfma_f32_16x16x32_bf16(af0[2 + s], bh, A0, 0, 0, 0);
                A1 = __builtin_amdgcn_mfma_f32_16x16x32_bf16(af1[2 + s], bh, A1, 0, 0, 0);
            }
            __syncthreads();  // frag reads done before next step's staging overwrites Hs
        }
        // Epilogue: lane owns (u0,bb) and (u1,bb).
        float hv0, hv1;
        {
            float gi = A0[0] + bi0, gf = A0[1] + bf0, gg = A0[2] + bg0, go = A0[3] + bo0;
            float ii = sigmoidf_(gi), ff = sigmoidf_(gf), g2 = tanhf_(gg), oo = sigmoidf_(go);
            cs0 = ff * cs0 + ii * g2;
            hv0 = oo * tanhf_(cs0);
        }
        {
            float gi = A1[0] + bi1, gf = A1[1] + bf1, gg = A1[2] + bg1, go = A1[3] + bo1;
            float ii = sigmoidf_(gi), ff = sigmoidf_(gf), g2 = tanhf_(gg), oo = sigmoidf_(go);
            cs1 = ff * cs1 + ii * g2;
            hv1 = oo * tanhf_(cs1);
        }
        if (t == TC_ - 1) {
            hfin[u0 * 64 + bb] = hv0;
            hfin[u1 * 64 + bb] = hv1;
        } else {
            // Publish: pack unit pairs via shfl (quad gets quad+1's value, same l16).
            ushort h0 = f2bf(hv0), h1 = f2bf(hv1);
            uint pr0 = ((uint)h0 & 0xFFFFu) | ((uint)__shfl((int)h0, (lane + 16) & 63) << 16);
            uint pr1 = ((uint)h1 & 0xFFFFu) | ((uint)__shfl((int)h1, (lane + 16) & 63) << 16);
            if ((quad & 1) == 0) {
                uint tg2 = ((uint)t) << 16;
                u64 w0 = (u64)((pr0 & 0xFFFFu) | tg2) | ((u64)((pr0 >> 16) | tg2) << 32);
                u64 w1 = (u64)((pr1 & 0xFFFFu) | tg2) | ((u64)((pr1 >> 16) | tg2) << 32);
                int pc = 32 * q + 4 * wave + (quad >> 1);  // tile0 pair cell
                u64* dst = hbuf + ((size_t)(t & 1) << 13) + p * 2048 + l16 * 128;
                __hip_atomic_store(dst + pc, w0, __ATOMIC_RELAXED, __HIP_MEMORY_SCOPE_AGENT);
                __hip_atomic_store(dst + pc + 2, w1, __ATOMIC_RELAXED, __HIP_MEMORY_SCOPE_AGENT);
            }
        }
        // Prefetch next xt (fire after publish; lands during next poll).
        int tn = (t + 1 < TC_) ? t + 1 : t;
        const ushort* xpn = li + ((size_t)tn * 64 + bb) * 72 + quad * 8;
        x0 = *(const bf16x8*)xpn;
        x1 = *(const bf16x8*)(xpn + 32);
    }
}

// ---- Kernel 5: out[b][o] = h_final[:,b] . lin_w[o,:] + lin_b[o] ----
__global__ __launch_bounds__(64) void k_fin(const float* __restrict__ hfin, const float* __restrict__ lw,
                                            const float* __restrict__ lb, float* __restrict__ out) {
    int o = blockIdx.x, b = threadIdx.x;
    float acc = lb[o];
    const float* wp = lw + o * 256;
#pragma unroll 4
    for (int u2 = 0; u2 < 256; ++u2) acc += hfin[u2 * 64 + b] * wp[u2];
    out[b * 10 + o] = acc;
}

extern "C" void kernel_launch(void* const* d_in, const int* in_sizes, int n_in,
                              void* d_out, int out_size, void* d_ws, size_t ws_size,
                              hipStream_t stream) {
    const float* in  = (const float*)d_in[0];
    // d_in[1] ("r") unused
    const float* cw  = (const float*)d_in[2];
    const float* cb  = (const float*)d_in[3];
    const float* wih = (const float*)d_in[4];
    const float* whh = (const float*)d_in[5];
    const float* bih = (const float*)d_in[6];
    const float* bhh = (const float*)d_in[7];
    const float* lw  = (const float*)d_in[8];
    const float* lb  = (const float*)d_in[9];
    float* out = (float*)d_out;

    char* ws = (char*)d_ws;
    float*  sq   = (float*)(ws + 0);          // 32768 B
    u64*    hbuf = (u64*)(ws + 32768);        // 131072 B: 2 parity x (4 pods x 2048 cells) x 8B
    float*  bias = (float*)(ws + 163840);     // 4096 B
    float*  hfin = (float*)(ws + 167936);     // 65536 B  [u][b] fp32
    ushort* wbf  = (ushort*)(ws + 233472);    // 655360 B [g2][16][320] bf16
    ushort* li   = (ushort*)(ws + 888832);    // 9418752 B [tc][b][72] bf16

    hipMemsetAsync(sq, 0, 32768, stream);
    hipMemsetAsync(hbuf, 0xFF, 131072, stream);  // tag fields -> 0xFFFF, never a valid step

    k_sqsum<<<1024, 128, 0, stream>>>(in, sq);
    k_prep<<<1280, 256, 0, stream>>>(wih, whh, bih, bhh, wbf, bias);
    k_conv<<<2048, 256, 0, stream>>>(in, cw, cb, sq, li);
    k_scan<<<16, 512, 0, stream>>>(li, wbf, bias, hbuf, hfin);
    k_fin<<<10, 64, 0, stream>>>(hfin, lw, lb, out);
}